// Round 14
// baseline (1103.249 us; speedup 1.0000x reference)
//
#include <hip/hip_runtime.h>
#include <hip/hip_bf16.h>
#include <stdint.h>

// Problem constants
#define NHEAD 8
#define DMODEL 512
#define DVOCAB 32000
#define M_DIM 4096            // B*P
#define K_DIM 4096            // NHEAD*DMODEL
#define N_DIM 32000           // DVOCAB
#define NT    64              // K_DIM / 64 k-tiles

typedef short bf16x8 __attribute__((ext_vector_type(8)));
typedef float f32x4 __attribute__((ext_vector_type(4)));
typedef unsigned short ushort8 __attribute__((ext_vector_type(8)));

template <int V> struct IC { static constexpr int v = V; };

__device__ __forceinline__ unsigned short f2bf(float f) {
    unsigned int u = __builtin_bit_cast(unsigned int, f);
    u = (u + 0x7fffu + ((u >> 16) & 1u)) >> 16;   // RNE (inputs are finite)
    return (unsigned short)u;
}

__device__ __forceinline__ void load16_to_lds(const void* g, void* l) {
    __builtin_amdgcn_global_load_lds(
        (const __attribute__((address_space(1))) unsigned int*)g,
        (__attribute__((address_space(3))) unsigned int*)l, 16, 0, 0);
}

// ---- x [4096][4096] f32 -> bf16, 8 elems/thread ----
__global__ void cvt_x(const float* __restrict__ in, unsigned short* __restrict__ out) {
    long t = (long)blockIdx.x * 256 + threadIdx.x;
    const float4* s = (const float4*)in + t * 2;
    float4 a = s[0], b = s[1];
    ushort8 o;
    o[0] = f2bf(a.x); o[1] = f2bf(a.y); o[2] = f2bf(a.z); o[3] = f2bf(a.w);
    o[4] = f2bf(b.x); o[5] = f2bf(b.y); o[6] = f2bf(b.z); o[7] = f2bf(b.w);
    *(ushort8*)(out + t * 8) = o;
}

// ---- W [H][V][D] f32 -> Wb [V][H*D] bf16 (B^T layout), 8 elems/thread ----
__global__ void cvt_w(const float* __restrict__ in, unsigned short* __restrict__ out) {
    int t = blockIdx.x * 256 + threadIdx.x;
    int d8 = t & 63;
    int hv = t >> 6;
    int h = hv / DVOCAB;
    int v = hv - h * DVOCAB;
    const float4* s = (const float4*)(in + (long)hv * DMODEL + d8 * 8);
    float4 a = s[0], b = s[1];
    ushort8 o;
    o[0] = f2bf(a.x); o[1] = f2bf(a.y); o[2] = f2bf(a.z); o[3] = f2bf(a.w);
    o[4] = f2bf(b.x); o[5] = f2bf(b.y); o[6] = f2bf(b.z); o[7] = f2bf(b.w);
    *(ushort8*)(out + (long)v * K_DIM + h * DMODEL + d8 * 8) = o;
}

// ---- bias [H][V] -> bsum [V] ----
__global__ void bias_red(const float* __restrict__ b, float* __restrict__ out) {
    int v = blockIdx.x * 256 + threadIdx.x;
    if (v >= DVOCAB) return;
    float s = 0.f;
    #pragma unroll
    for (int h = 0; h < NHEAD; ++h) s += b[h * DVOCAB + v];
    out[v] = s;
}

#define BAR()    __builtin_amdgcn_s_barrier()
#define VMCNT6() asm volatile("s_waitcnt vmcnt(6)" ::: "memory")
#define VMCNT0() asm volatile("s_waitcnt vmcnt(0)" ::: "memory")

// ---- bf16 GEMM, 256x256 tile, BK=64, read-overlap 3-phase schedule ----
// C[M,N] = A[M,K] * Bt[N,K]^T + bias
// vs r13: quad order q00,q10,q01,q11; bf1+afH reads issued AFTER BAR1 and
// BEFORE q00 so their drain hides under q00's 16 MFMAs (compiler emits
// counted lgkm: q00 waits only afL/bf0). FIFO property of DS completion:
// q10's afH-wait implies bf1 complete -> by BAR3 all of tile t's B1 reads
// are done -> staging (t+2).B1 at P3 is race-free.
// Hazard ledger (stage X while old readers outstanding):
//  - (t+1).A1 @P1: old afH readers finished at t-1.P2 (q10 wait) ✓
//  - (t+2).A0 @P2: afL reads complete by q00's wait (FIFO, before BAR2) ✓
//  - (t+2).B0 @P3: bf0 reads complete by q00's wait ✓ (>=1 BAR before)
//  - (t+2).B1 @P3: bf1 reads complete by q10's afH-wait (FIFO), BAR3 ✓
// vmcnt ledger: entering t, outstanding = (t+1).{A0,B0,B1} (6). +A1@P1 (8),
//  +A0@P2 (10), +B0,B1@P3 (14); vmcnt(6) drains 8 oldest = all of t+1 ✓,
//  leaves (t+2).{A0,B0,B1} = 6 = invariant. Tails: t>=NT-2 -> vmcnt(0).
// Register bill: 8 staging cursors -> 1 (lockstep +128B/tile; fixed offsets).
__global__ __launch_bounds__(512, 2) void gemm256(
    const unsigned short* __restrict__ A,   // [4096][4096] bf16
    const unsigned short* __restrict__ B,   // [32000][4096] bf16
    const float* __restrict__ bias,         // [32000]
    float* __restrict__ C)                  // [4096][32000] f32
{
    __shared__ __attribute__((aligned(16))) unsigned short lds[2][2][2][8192];

    const int tid = threadIdx.x;
    const int bid = blockIdx.x;
    // Locality swizzle (r8-proven): XCD owns 2 M-bands; nt time-synced sweep.
    const int xcd = bid & 7, j = bid >> 3;   // j in 0..249
    const int mt = xcd * 2 + (j & 1);        // 16 M-tiles
    const int nt = j >> 1;                   // 125 N-tiles
    const long m0 = (long)mt * 256;
    const long n0 = (long)nt * 256;

    const int wid = tid >> 6, lane = tid & 63;
    const int wr = wid >> 2, wc = wid & 3;     // 2 x 4 waves
    const int lr = lane & 15, lk = lane >> 4;
    const int swz = lr & 7;                    // row&7 == lr&7 for all frag rows

    // ds_read base pointers: 4 VGPRs, everything else immediate offsets
    const unsigned short* pA[2];
    const unsigned short* pB[2];
    #pragma unroll
    for (int ks = 0; ks < 2; ++ks) {
        const int ch = ((ks << 2) | lk) ^ swz;
        pA[ks] = &lds[0][0][0][0] + (wr * 64 + lr) * 64 + ch * 8;
        pB[ks] = &lds[1][0][0][0] + (wc * 32 + lr) * 64 + ch * 8;
    }
    // frag read: [rows of 16][half][buf] as compile-time immediates (<64KiB)
    #define LDA(mi, ks, HALF, CURB) \
        (*(const bf16x8*)(pA[ks] + (mi) * 1024 + (HALF) * 16384 + (CURB) * 8192))
    #define LDB(nj, ks, HALF, CURB) \
        (*(const bf16x8*)(pB[ks] + (nj) * 1024 + (HALF) * 16384 + (CURB) * 8192))

    // staging: ONE per-lane cursor; region offsets are compile-time constants.
    // rows: +64 rows = 0x80000 B, +128 rows = 0x100000 B (K=4096, 2B/elem).
    const char* Ab = (const char*)(A + m0 * K_DIM);
    const char* Bb = (const char*)(B + n0 * K_DIM);
    const int row0 = tid >> 3,         c0 = (tid & 7) ^ (row0 & 7);
    const int row1 = (512 + tid) >> 3, c1 = ((512 + tid) & 7) ^ (row1 & 7);
    unsigned int cur0 = (unsigned)(row0 * K_DIM + c0 * 8) * 2u;
    const unsigned int d01 = (unsigned)((row1 - row0) * K_DIM + (c1 - c0) * 8) * 2u;

    #define ST_A0(CURB) do { \
        load16_to_lds(Ab + cur0,       (char*)&lds[0][0][(CURB)][0] + tid * 16); \
        load16_to_lds(Ab + cur0 + d01, (char*)&lds[0][0][(CURB)][0] + 8192 + tid * 16); \
    } while (0)
    #define ST_A1(CURB) do { \
        load16_to_lds(Ab + cur0 + 0x100000u,       (char*)&lds[0][1][(CURB)][0] + tid * 16); \
        load16_to_lds(Ab + cur0 + 0x100000u + d01, (char*)&lds[0][1][(CURB)][0] + 8192 + tid * 16); \
    } while (0)
    #define ST_B0(CURB) do { \
        load16_to_lds(Bb + cur0,       (char*)&lds[1][0][(CURB)][0] + tid * 16); \
        load16_to_lds(Bb + cur0 + d01, (char*)&lds[1][0][(CURB)][0] + 8192 + tid * 16); \
    } while (0)
    #define ST_B1(CURB) do { \
        load16_to_lds(Bb + cur0 + 0x100000u,       (char*)&lds[1][1][(CURB)][0] + tid * 16); \
        load16_to_lds(Bb + cur0 + 0x100000u + d01, (char*)&lds[1][1][(CURB)][0] + 8192 + tid * 16); \
    } while (0)

    // NOTE: cursor advances once per STAGED TILE (+128B). Stages for tile u
    // happen across phases of tile u-2/u-1; we advance at the last stage (B1).

    // MFMA quad: 16 MFMAs, ks outermost (dependent same-acc pairs 8 apart)
    #define MFQUAD(AF, BF, MO, NO) do {                                        \
        _Pragma("unroll")                                                      \
        for (int ks = 0; ks < 2; ++ks)                                         \
            _Pragma("unroll")                                                  \
            for (int mi = 0; mi < 4; ++mi)                                     \
                _Pragma("unroll")                                              \
                for (int nj = 0; nj < 2; ++nj)                                 \
                    acc[(MO) + mi][(NO) + nj] =                                \
                        __builtin_amdgcn_mfma_f32_16x16x32_bf16(               \
                            AF[mi][ks], BF[nj][ks], acc[(MO) + mi][(NO) + nj], \
                            0, 0, 0);                                          \
    } while (0)

    f32x4 acc[8][4];
    #pragma unroll
    for (int i = 0; i < 8; ++i)
        #pragma unroll
        for (int jn = 0; jn < 4; ++jn)
            acc[i][jn] = (f32x4){0.f, 0.f, 0.f, 0.f};

    bf16x8 afL[4][2], afH[4][2], bf0[2][2], bf1[2][2];

    // prologue: tile0 fully (cursor at tile0); advance; tile1 {A0,B0,B1}
    ST_A0(0); ST_B0(0); ST_B1(0); ST_A1(0);
    cur0 += 128;
    ST_A0(1); ST_B0(1); ST_B1(1);
    // cursor now points at tile1; tile1's A1 will be staged at t=0.P1,
    // then cursor advances to tile2 before t=0.P2 stages (t+2).A0.
    VMCNT6();
    BAR();

    auto body = [&](auto curc, int t) {
        constexpr int CUR = decltype(curc)::v;

        // ---- P1: read afL(8)+bf0(4); stage (t+1).A1; BAR;
        //          read bf1(4) then afH(8) [drain under q00]; q00; BAR
        #pragma unroll
        for (int mi = 0; mi < 4; ++mi) {
            afL[mi][0] = LDA(mi, 0, 0, CUR);
            afL[mi][1] = LDA(mi, 1, 0, CUR);
        }
        #pragma unroll
        for (int nj = 0; nj < 2; ++nj) {
            bf0[nj][0] = LDB(nj, 0, 0, CUR);
            bf0[nj][1] = LDB(nj, 1, 0, CUR);
        }
        if (t + 1 < NT) { ST_A1(CUR ^ 1); }
        cur0 += 128;     // cursor: tile t+1 -> tile t+2
        BAR();
        #pragma unroll
        for (int nj = 0; nj < 2; ++nj) {            // bf1 FIRST (FIFO)
            bf1[nj][0] = LDB(nj, 0, 1, CUR);
            bf1[nj][1] = LDB(nj, 1, 1, CUR);
        }
        #pragma unroll
        for (int mi = 0; mi < 4; ++mi) {            // then afH
            afH[mi][0] = LDA(mi, 0, 1, CUR);
            afH[mi][1] = LDA(mi, 1, 1, CUR);
        }
        __builtin_amdgcn_s_setprio(1);
        MFQUAD(afL, bf0, 0, 0);
        __builtin_amdgcn_s_setprio(0);
        BAR();

        // ---- P2: stage (t+2).A0; q10 (afH-wait => bf1 complete); BAR
        if (t + 2 < NT) ST_A0(CUR);
        __builtin_amdgcn_s_setprio(1);
        MFQUAD(afH, bf0, 4, 0);
        __builtin_amdgcn_s_setprio(0);
        BAR();

        // ---- P3: stage (t+2).B0+B1; counted vmcnt; BAR; q01+q11; BAR
        if (t + 2 < NT) { ST_B0(CUR); ST_B1(CUR); }
        if (t < NT - 2) { VMCNT6(); } else { VMCNT0(); }
        BAR();
        __builtin_amdgcn_s_setprio(1);
        MFQUAD(afL, bf1, 0, 2);
        MFQUAD(afH, bf1, 4, 2);
        __builtin_amdgcn_s_setprio(0);
        BAR();
    };

    for (int t = 0; t < NT; t += 2) {
        body(IC<0>{}, t);
        body(IC<1>{}, t + 1);
    }
    #undef LDA
    #undef LDB
    #undef ST_A0
    #undef ST_A1
    #undef ST_B0
    #undef ST_B1
    #undef MFQUAD

    // epilogue: C/D layout col = lane&15 (lr), row = lk*4 + reg; nontemporal
    #pragma unroll
    for (int nj = 0; nj < 4; ++nj) {
        const long col = n0 + (nj >> 1) * 128 + wc * 32 + (nj & 1) * 16 + lr;
        const float bs = bias[col];
        #pragma unroll
        for (int mi = 0; mi < 8; ++mi) {
            const long row = m0 + (mi >> 2) * 128 + wr * 64 + (mi & 3) * 16 + lk * 4;
            #pragma unroll
            for (int r = 0; r < 4; ++r)
                __builtin_nontemporal_store(acc[mi][nj][r] + bs,
                                            &C[(row + r) * (long)N_DIM + col]);
        }
    }
}

// ---- emergency fallback if ws too small: naive fp32 (slow but correct) ----
__global__ void naive_out(const float* __restrict__ x, const float* __restrict__ w,
                          const float* __restrict__ b, float* __restrict__ out) {
    long idx = (long)blockIdx.x * 256 + threadIdx.x;
    if (idx >= (long)M_DIM * N_DIM) return;
    long m = idx / N_DIM;
    int v = (int)(idx - m * N_DIM);
    float s = 0.f;
    for (int h = 0; h < NHEAD; ++h) {
        const float* xr = x + m * K_DIM + h * DMODEL;
        const float* wr = w + ((long)h * DVOCAB + v) * DMODEL;
        float ps = 0.f;
        for (int d = 0; d < DMODEL; ++d) ps += xr[d] * wr[d];
        s += ps + b[h * DVOCAB + v];
    }
    out[idx] = s;
}

extern "C" void kernel_launch(void* const* d_in, const int* in_sizes, int n_in,
                              void* d_out, int out_size, void* d_ws, size_t ws_size,
                              hipStream_t stream) {
    const float* x = (const float*)d_in[0];   // [8,512,8,512]
    const float* w = (const float*)d_in[1];   // [8,32000,512]
    const float* b = (const float*)d_in[2];   // [8,32000]
    float* out = (float*)d_out;               // [8,512,32000]

    const size_t xbf_bytes = (size_t)M_DIM * K_DIM * 2;
    const size_t wbf_bytes = (size_t)N_DIM * K_DIM * 2;
    const size_t bs_bytes  = (size_t)N_DIM * 4;
    const size_t need = xbf_bytes + wbf_bytes + bs_bytes;

    if (ws_size < need) {
        long total = (long)M_DIM * N_DIM;
        int blocks = (int)((total + 255) / 256);
        naive_out<<<blocks, 256, 0, stream>>>(x, w, b, out);
        return;
    }

    unsigned short* xbf = (unsigned short*)d_ws;
    unsigned short* wbf = (unsigned short*)((char*)d_ws + xbf_bytes);
    float* bsum = (float*)((char*)d_ws + xbf_bytes + wbf_bytes);

    cvt_x<<<8192, 256, 0, stream>>>(x, xbf);
    cvt_w<<<64000, 256, 0, stream>>>(w, wbf);
    bias_red<<<125, 256, 0, stream>>>(b, bsum);
    gemm256<<<2000, 512, 0, stream>>>(xbf, wbf, bsum, out);  // 16 x 125 tiles
}

// Round 15
// 1087.676 us; speedup vs baseline: 1.0143x; 1.0143x over previous
//
#include <hip/hip_runtime.h>
#include <hip/hip_bf16.h>
#include <stdint.h>

// Problem constants
#define NHEAD 8
#define DMODEL 512
#define DVOCAB 32000
#define M_DIM 4096            // B*P
#define K_DIM 4096            // NHEAD*DMODEL
#define N_DIM 32000           // DVOCAB
#define NT    64              // K_DIM / 64 k-tiles per output tile

typedef short bf16x8 __attribute__((ext_vector_type(8)));
typedef float f32x4 __attribute__((ext_vector_type(4)));
typedef unsigned short ushort8 __attribute__((ext_vector_type(8)));

template <int V> struct IC { static constexpr int v = V; };

__device__ __forceinline__ unsigned short f2bf(float f) {
    unsigned int u = __builtin_bit_cast(unsigned int, f);
    u = (u + 0x7fffu + ((u >> 16) & 1u)) >> 16;   // RNE (inputs are finite)
    return (unsigned short)u;
}

__device__ __forceinline__ void load16_to_lds(const void* g, void* l) {
    __builtin_amdgcn_global_load_lds(
        (const __attribute__((address_space(1))) unsigned int*)g,
        (__attribute__((address_space(3))) unsigned int*)l, 16, 0, 0);
}

// ---- x [4096][4096] f32 -> bf16, 8 elems/thread ----
__global__ void cvt_x(const float* __restrict__ in, unsigned short* __restrict__ out) {
    long t = (long)blockIdx.x * 256 + threadIdx.x;
    const float4* s = (const float4*)in + t * 2;
    float4 a = s[0], b = s[1];
    ushort8 o;
    o[0] = f2bf(a.x); o[1] = f2bf(a.y); o[2] = f2bf(a.z); o[3] = f2bf(a.w);
    o[4] = f2bf(b.x); o[5] = f2bf(b.y); o[6] = f2bf(b.z); o[7] = f2bf(b.w);
    *(ushort8*)(out + t * 8) = o;
}

// ---- W [H][V][D] f32 -> Wb [V][H*D] bf16 (B^T layout), 8 elems/thread ----
__global__ void cvt_w(const float* __restrict__ in, unsigned short* __restrict__ out) {
    int t = blockIdx.x * 256 + threadIdx.x;
    int d8 = t & 63;
    int hv = t >> 6;
    int h = hv / DVOCAB;
    int v = hv - h * DVOCAB;
    const float4* s = (const float4*)(in + (long)hv * DMODEL + d8 * 8);
    float4 a = s[0], b = s[1];
    ushort8 o;
    o[0] = f2bf(a.x); o[1] = f2bf(a.y); o[2] = f2bf(a.z); o[3] = f2bf(a.w);
    o[4] = f2bf(b.x); o[5] = f2bf(b.y); o[6] = f2bf(b.z); o[7] = f2bf(b.w);
    *(ushort8*)(out + (long)v * K_DIM + h * DMODEL + d8 * 8) = o;
}

// ---- bias [H][V] -> bsum [V] ----
__global__ void bias_red(const float* __restrict__ b, float* __restrict__ out) {
    int v = blockIdx.x * 256 + threadIdx.x;
    if (v >= DVOCAB) return;
    float s = 0.f;
    #pragma unroll
    for (int h = 0; h < NHEAD; ++h) s += b[h * DVOCAB + v];
    out[v] = s;
}

#define BAR()    __builtin_amdgcn_s_barrier()
#define VMCNT6() asm volatile("s_waitcnt vmcnt(6)" ::: "memory")
#define VMCNT0() asm volatile("s_waitcnt vmcnt(0)" ::: "memory")

// ---- bf16 GEMM, persistent blocks: 250 blocks (1/CU), 8 output tiles each ----
// C[M,N] = A[M,K] * Bt[N,K]^T + bias
// Block b: nt = b%125 FIXED (B-panel + bias reused), walks mt = (b/125)*8 + i.
// K-loop = r12's verified 3-phase schedule; staging index u = t+1 / t+2 WRAPS
// across the tile boundary (u>=NT -> next tile's A base, u-NT) so the
// vmcnt(6) pipeline never drains between tiles; prologue runs once per block
// instead of once per tile. NT even -> LDS buffer parity continuous. Epilogue
// (nontemporal stores, complete at L2) overlaps the in-flight staging.
// Hazard ledger identical to r12 steady state at every t including wrap:
//   A1(u1) staged at P1 over buf[(u1)&1].A1, last read at (u1-2).P3' ✓
//   A0/B0/B1(u2) staged at P2/P3' over regions last read this tile's P1/P2 ✓
//   vmcnt(6)@P3' drains through tile t+1 (FIFO count, wrap-agnostic) ✓
__global__ __launch_bounds__(512, 2) void gemm256(
    const unsigned short* __restrict__ A,   // [4096][4096] bf16
    const unsigned short* __restrict__ B,   // [32000][4096] bf16
    const float* __restrict__ bias,         // [32000]
    float* __restrict__ C)                  // [4096][32000] f32
{
    __shared__ __attribute__((aligned(16))) unsigned short lds[2][2][2][8192];

    const int tid = threadIdx.x;
    const int bid = blockIdx.x;              // 250 blocks
    const int nt  = bid % 125;
    const int mh  = bid / 125;               // 0..1 (8 mt-tiles each)
    const long n0 = (long)nt * 256;

    const int wid = tid >> 6, lane = tid & 63;
    const int wr = wid >> 2, wc = wid & 3;     // 2 x 4 waves
    const int lr = lane & 15, lk = lane >> 4;
    const int swz = lr & 7;                    // row&7 == lr&7 for all frag rows

    // ds_read base pointers: 4 VGPRs, everything else immediate offsets
    const unsigned short* pA[2];
    const unsigned short* pB[2];
    #pragma unroll
    for (int ks = 0; ks < 2; ++ks) {
        const int ch = ((ks << 2) | lk) ^ swz;
        pA[ks] = &lds[0][0][0][0] + (wr * 64 + lr) * 64 + ch * 8;
        pB[ks] = &lds[1][0][0][0] + (wc * 32 + lr) * 64 + ch * 8;
    }
    #define LDA(mi, ks, HALF, CURB) \
        (*(const bf16x8*)(pA[ks] + (mi) * 1024 + (HALF) * 16384 + (CURB) * 8192))
    #define LDB(nj, ks, HALF, CURB) \
        (*(const bf16x8*)(pB[ks] + (nj) * 1024 + (HALF) * 16384 + (CURB) * 8192))

    // staging lane constants; k-tile u adds (u<<7) bytes; +128 rows = 0x100000
    const int row0 = tid >> 3,         c0 = (tid & 7) ^ (row0 & 7);
    const int row1 = (512 + tid) >> 3, c1 = ((512 + tid) & 7) ^ (row1 & 7);
    const unsigned int lo0 = (unsigned)(row0 * K_DIM + c0 * 8) * 2u;
    const unsigned int d01 = (unsigned)((row1 - row0) * K_DIM + (c1 - c0) * 8) * 2u;

    const char* Ab_i = (const char*)A + (size_t)mh * 8 * 0x200000u;  // tile i A base
    const char* Ab_n = Ab_i + 0x200000u;                             // tile i+1
    const char* Bb   = (const char*)(B + n0 * K_DIM);                // fixed

    #define ST_A0(CURB, AB, UW) do { \
        load16_to_lds((AB) + lo0 + ((unsigned)(UW) << 7),       (char*)&lds[0][0][(CURB)][0] + tid * 16); \
        load16_to_lds((AB) + lo0 + d01 + ((unsigned)(UW) << 7), (char*)&lds[0][0][(CURB)][0] + 8192 + tid * 16); \
    } while (0)
    #define ST_A1(CURB, AB, UW) do { \
        load16_to_lds((AB) + lo0 + 0x100000u + ((unsigned)(UW) << 7),       (char*)&lds[0][1][(CURB)][0] + tid * 16); \
        load16_to_lds((AB) + lo0 + 0x100000u + d01 + ((unsigned)(UW) << 7), (char*)&lds[0][1][(CURB)][0] + 8192 + tid * 16); \
    } while (0)
    #define ST_B0(CURB, UW) do { \
        load16_to_lds(Bb + lo0 + ((unsigned)(UW) << 7),       (char*)&lds[1][0][(CURB)][0] + tid * 16); \
        load16_to_lds(Bb + lo0 + d01 + ((unsigned)(UW) << 7), (char*)&lds[1][0][(CURB)][0] + 8192 + tid * 16); \
    } while (0)
    #define ST_B1(CURB, UW) do { \
        load16_to_lds(Bb + lo0 + 0x100000u + ((unsigned)(UW) << 7),       (char*)&lds[1][1][(CURB)][0] + tid * 16); \
        load16_to_lds(Bb + lo0 + 0x100000u + d01 + ((unsigned)(UW) << 7), (char*)&lds[1][1][(CURB)][0] + 8192 + tid * 16); \
    } while (0)

    #define MFQUAD(AF, BF, MO, NO) do {                                        \
        _Pragma("unroll")                                                      \
        for (int ks = 0; ks < 2; ++ks)                                         \
            _Pragma("unroll")                                                  \
            for (int mi = 0; mi < 4; ++mi)                                     \
                _Pragma("unroll")                                              \
                for (int nj = 0; nj < 2; ++nj)                                 \
                    acc[(MO) + mi][(NO) + nj] =                                \
                        __builtin_amdgcn_mfma_f32_16x16x32_bf16(               \
                            AF[mi][ks], BF[nj][ks], acc[(MO) + mi][(NO) + nj], \
                            0, 0, 0);                                          \
    } while (0)

    f32x4 acc[8][4];
    #pragma unroll
    for (int i = 0; i < 8; ++i)
        #pragma unroll
        for (int jn = 0; jn < 4; ++jn)
            acc[i][jn] = (f32x4){0.f, 0.f, 0.f, 0.f};

    // bias hoisted: nt (cols) fixed for the whole block
    float bs[4];
    #pragma unroll
    for (int nj = 0; nj < 4; ++nj)
        bs[nj] = bias[n0 + (nj >> 1) * 128 + wc * 32 + (nj & 1) * 16 + lr];

    bf16x8 af[4][2], bf0[2][2], bf1[2][2];

    // ONE prologue per block: tile0.K0 fully + tile0.K1 {A0,B0,B1}
    ST_A0(0, Ab_i, 0); ST_B0(0, 0); ST_B1(0, 0); ST_A1(0, Ab_i, 0);
    ST_A0(1, Ab_i, 1); ST_B0(1, 1); ST_B1(1, 1);
    VMCNT6();
    BAR();

    auto body = [&](auto curc, int t, bool lastT) {
        constexpr int CUR = decltype(curc)::v;
        int u1 = t + 1; const char* AS1 = Ab_i; if (u1 >= NT) { u1 -= NT; AS1 = Ab_n; }
        int u2 = t + 2; const char* AS2 = Ab_i; if (u2 >= NT) { u2 -= NT; AS2 = Ab_n; }
        const bool st1 = !lastT || (t + 1 < NT);
        const bool st2 = !lastT || (t + 2 < NT);

        // ---- P1: read A-h0(8) + B-h0(4); stage A1(u1); q00
        #pragma unroll
        for (int mi = 0; mi < 4; ++mi) {
            af[mi][0] = LDA(mi, 0, 0, CUR);
            af[mi][1] = LDA(mi, 1, 0, CUR);
        }
        #pragma unroll
        for (int nj = 0; nj < 2; ++nj) {
            bf0[nj][0] = LDB(nj, 0, 0, CUR);
            bf0[nj][1] = LDB(nj, 1, 0, CUR);
        }
        if (st1) ST_A1(CUR ^ 1, AS1, u1);
        BAR();
        __builtin_amdgcn_s_setprio(1);
        MFQUAD(af, bf0, 0, 0);
        __builtin_amdgcn_s_setprio(0);
        BAR();

        // ---- P2: read B-h1(4); stage A0(u2); q01
        #pragma unroll
        for (int nj = 0; nj < 2; ++nj) {
            bf1[nj][0] = LDB(nj, 0, 1, CUR);
            bf1[nj][1] = LDB(nj, 1, 1, CUR);
        }
        if (st2) ST_A0(CUR, AS2, u2);
        BAR();
        __builtin_amdgcn_s_setprio(1);
        MFQUAD(af, bf1, 0, 2);
        __builtin_amdgcn_s_setprio(0);
        BAR();

        // ---- P3' (merged): read A-h1(8); stage B0(u2)+B1(u2); vmcnt; q10+q11
        #pragma unroll
        for (int mi = 0; mi < 4; ++mi) {
            af[mi][0] = LDA(mi, 0, 1, CUR);
            af[mi][1] = LDA(mi, 1, 1, CUR);
        }
        if (st2) { ST_B0(CUR, u2); ST_B1(CUR, u2); }
        if (lastT && t >= NT - 2) { VMCNT0(); } else { VMCNT6(); }
        BAR();
        __builtin_amdgcn_s_setprio(1);
        MFQUAD(af, bf0, 4, 0);
        MFQUAD(af, bf1, 4, 2);
        __builtin_amdgcn_s_setprio(0);
        BAR();
    };

    for (int i = 0; i < 8; ++i) {
        const bool lastT = (i == 7);
        for (int t = 0; t < NT; t += 2) {
            body(IC<0>{}, t, lastT);
            body(IC<1>{}, t + 1, lastT);
        }
        // epilogue tile i: stores overlap next tile's in-flight staging
        const long m0i = (long)(mh * 8 + i) * 256;
        #pragma unroll
        for (int nj = 0; nj < 4; ++nj) {
            const long col = n0 + (nj >> 1) * 128 + wc * 32 + (nj & 1) * 16 + lr;
            #pragma unroll
            for (int mi = 0; mi < 8; ++mi) {
                const long row = m0i + (mi >> 2) * 128 + wr * 64 + (mi & 3) * 16 + lk * 4;
                #pragma unroll
                for (int r = 0; r < 4; ++r)
                    __builtin_nontemporal_store(acc[mi][nj][r] + bs[nj],
                                                &C[(row + r) * (long)N_DIM + col]);
                acc[mi][nj] = (f32x4){0.f, 0.f, 0.f, 0.f};
            }
        }
        Ab_i = Ab_n; Ab_n += 0x200000u;
    }
    #undef LDA
    #undef LDB
    #undef ST_A0
    #undef ST_A1
    #undef ST_B0
    #undef ST_B1
    #undef MFQUAD
}

// ---- emergency fallback if ws too small: naive fp32 (slow but correct) ----
__global__ void naive_out(const float* __restrict__ x, const float* __restrict__ w,
                          const float* __restrict__ b, float* __restrict__ out) {
    long idx = (long)blockIdx.x * 256 + threadIdx.x;
    if (idx >= (long)M_DIM * N_DIM) return;
    long m = idx / N_DIM;
    int v = (int)(idx - m * N_DIM);
    float s = 0.f;
    for (int h = 0; h < NHEAD; ++h) {
        const float* xr = x + m * K_DIM + h * DMODEL;
        const float* wr = w + ((long)h * DVOCAB + v) * DMODEL;
        float ps = 0.f;
        for (int d = 0; d < DMODEL; ++d) ps += xr[d] * wr[d];
        s += ps + b[h * DVOCAB + v];
    }
    out[idx] = s;
}

extern "C" void kernel_launch(void* const* d_in, const int* in_sizes, int n_in,
                              void* d_out, int out_size, void* d_ws, size_t ws_size,
                              hipStream_t stream) {
    const float* x = (const float*)d_in[0];   // [8,512,8,512]
    const float* w = (const float*)d_in[1];   // [8,32000,512]
    const float* b = (const float*)d_in[2];   // [8,32000]
    float* out = (float*)d_out;               // [8,512,32000]

    const size_t xbf_bytes = (size_t)M_DIM * K_DIM * 2;
    const size_t wbf_bytes = (size_t)N_DIM * K_DIM * 2;
    const size_t bs_bytes  = (size_t)N_DIM * 4;
    const size_t need = xbf_bytes + wbf_bytes + bs_bytes;

    if (ws_size < need) {
        long total = (long)M_DIM * N_DIM;
        int blocks = (int)((total + 255) / 256);
        naive_out<<<blocks, 256, 0, stream>>>(x, w, b, out);
        return;
    }

    unsigned short* xbf = (unsigned short*)d_ws;
    unsigned short* wbf = (unsigned short*)((char*)d_ws + xbf_bytes);
    float* bsum = (float*)((char*)d_ws + xbf_bytes + wbf_bytes);

    cvt_x<<<8192, 256, 0, stream>>>(x, xbf);
    cvt_w<<<64000, 256, 0, stream>>>(w, wbf);
    bias_red<<<125, 256, 0, stream>>>(b, bsum);
    gemm256<<<250, 512, 0, stream>>>(xbf, wbf, bsum, out);  // persistent: 8 tiles/block
}

// Round 16
// 1065.703 us; speedup vs baseline: 1.0352x; 1.0206x over previous
//
#include <hip/hip_runtime.h>
#include <hip/hip_bf16.h>
#include <stdint.h>

// Problem constants
#define NHEAD 8
#define DMODEL 512
#define DVOCAB 32000
#define M_DIM 4096            // B*P
#define K_DIM 4096            // NHEAD*DMODEL
#define N_DIM 32000           // DVOCAB
#define NT    64              // K_DIM / 64 k-tiles

typedef short bf16x8 __attribute__((ext_vector_type(8)));
typedef float f32x4 __attribute__((ext_vector_type(4)));
typedef unsigned short ushort8 __attribute__((ext_vector_type(8)));

template <int V> struct IC { static constexpr int v = V; };

__device__ __forceinline__ unsigned short f2bf(float f) {
    unsigned int u = __builtin_bit_cast(unsigned int, f);
    u = (u + 0x7fffu + ((u >> 16) & 1u)) >> 16;   // RNE (inputs are finite)
    return (unsigned short)u;
}

__device__ __forceinline__ void load16_to_lds(const void* g, void* l) {
    __builtin_amdgcn_global_load_lds(
        (const __attribute__((address_space(1))) unsigned int*)g,
        (__attribute__((address_space(3))) unsigned int*)l, 16, 0, 0);
}

// ---- fused prep: W->bf16 (B^T layout) + x->bf16 + bias reduce, one dispatch ----
// blocks [0,64000): cvt_w; [64000,72192): cvt_x; [72192,72317): bias_red.
#define PREP_W_BLOCKS 64000
#define PREP_X_BLOCKS 8192
#define PREP_B_BLOCKS 125
__global__ void prep(const float* __restrict__ w, const float* __restrict__ x,
                     const float* __restrict__ b,
                     unsigned short* __restrict__ wbf,
                     unsigned short* __restrict__ xbf,
                     float* __restrict__ bsum) {
    const int bb = blockIdx.x;
    if (bb < PREP_W_BLOCKS) {
        int t = bb * 256 + threadIdx.x;
        int d8 = t & 63;
        int hv = t >> 6;
        int h = hv / DVOCAB;
        int v = hv - h * DVOCAB;
        const float4* s = (const float4*)(w + (long)hv * DMODEL + d8 * 8);
        float4 a = s[0], c = s[1];
        ushort8 o;
        o[0] = f2bf(a.x); o[1] = f2bf(a.y); o[2] = f2bf(a.z); o[3] = f2bf(a.w);
        o[4] = f2bf(c.x); o[5] = f2bf(c.y); o[6] = f2bf(c.z); o[7] = f2bf(c.w);
        *(ushort8*)(wbf + (long)v * K_DIM + h * DMODEL + d8 * 8) = o;
    } else if (bb < PREP_W_BLOCKS + PREP_X_BLOCKS) {
        long t = (long)(bb - PREP_W_BLOCKS) * 256 + threadIdx.x;
        const float4* s = (const float4*)x + t * 2;
        float4 a = s[0], c = s[1];
        ushort8 o;
        o[0] = f2bf(a.x); o[1] = f2bf(a.y); o[2] = f2bf(a.z); o[3] = f2bf(a.w);
        o[4] = f2bf(c.x); o[5] = f2bf(c.y); o[6] = f2bf(c.z); o[7] = f2bf(c.w);
        *(ushort8*)(xbf + t * 8) = o;
    } else {
        int v = (bb - PREP_W_BLOCKS - PREP_X_BLOCKS) * 256 + threadIdx.x;
        if (v >= DVOCAB) return;
        float s = 0.f;
        #pragma unroll
        for (int h = 0; h < NHEAD; ++h) s += b[h * DVOCAB + v];
        bsum[v] = s;
    }
}

#define BAR()    __builtin_amdgcn_s_barrier()
#define VMCNT6() asm volatile("s_waitcnt vmcnt(6)" ::: "memory")
#define VMCNT0() asm volatile("s_waitcnt vmcnt(0)" ::: "memory")

// ---- bf16 GEMM, 256x256 tile, BK=64, 3-phase (r13 config — best verified) ----
// C[M,N] = A[M,K] * Bt[N,K]^T + bias
// Measured (r13): GEMM 1011-1043 us, MfmaUtil 48.6%, 0 bank conflicts,
// FETCH 1.156 GB, WRITE 546 MB. This is the {reads;BAR;MFMA;BAR} family's
// measured ceiling on this shape (7 structural variants all land 48-50%).
// Hazard ledger (per tile t, CUR=t&1):
//  - (t+1).A1 -> buf^1 @P1: last read at t-1.P3' (afH), complete before its
//    trailing BAR ✓
//  - (t+2).A0 -> buf[CUR] @P2: A0 last read t.P1 -> P1-end BAR ✓
//  - (t+2).B0,B1 -> buf[CUR] @P3': B0 last read t.P1, B1 last read t.P2 ✓
//  - vmcnt(6) @P3': drains through tile t+1; (t+2).{A0,B0,B1}=6 remain ✓
//  - tails: t >= NT-2 -> vmcnt(0) ✓
__global__ __launch_bounds__(512, 2) void gemm256(
    const unsigned short* __restrict__ A,   // [4096][4096] bf16
    const unsigned short* __restrict__ B,   // [32000][4096] bf16
    const float* __restrict__ bias,         // [32000]
    float* __restrict__ C)                  // [4096][32000] f32
{
    __shared__ __attribute__((aligned(16))) unsigned short lds[2][2][2][8192];

    const int tid = threadIdx.x;
    const int bid = blockIdx.x;
    // Locality swizzle (r8-proven): XCD owns 2 M-bands; nt time-synced sweep.
    const int xcd = bid & 7, j = bid >> 3;   // j in 0..249
    const int mt = xcd * 2 + (j & 1);        // 16 M-tiles
    const int nt = j >> 1;                   // 125 N-tiles
    const long m0 = (long)mt * 256;
    const long n0 = (long)nt * 256;

    const int wid = tid >> 6, lane = tid & 63;
    const int wr = wid >> 2, wc = wid & 3;     // 2 x 4 waves
    const int lr = lane & 15, lk = lane >> 4;
    const int swz = lr & 7;                    // row&7 == lr&7 for all frag rows

    // ds_read base pointers: 4 VGPRs, everything else immediate offsets
    const unsigned short* pA[2];
    const unsigned short* pB[2];
    #pragma unroll
    for (int ks = 0; ks < 2; ++ks) {
        const int ch = ((ks << 2) | lk) ^ swz;
        pA[ks] = &lds[0][0][0][0] + (wr * 64 + lr) * 64 + ch * 8;
        pB[ks] = &lds[1][0][0][0] + (wc * 32 + lr) * 64 + ch * 8;
    }
    #define LDA(mi, ks, HALF, CURB) \
        (*(const bf16x8*)(pA[ks] + (mi) * 1024 + (HALF) * 16384 + (CURB) * 8192))
    #define LDB(nj, ks, HALF, CURB) \
        (*(const bf16x8*)(pB[ks] + (nj) * 1024 + (HALF) * 16384 + (CURB) * 8192))

    // staging: per-lane 32-bit byte offsets off uniform bases, advanced +128B/use
    const char* Ab = (const char*)(A + m0 * K_DIM);
    const char* Bb = (const char*)(B + n0 * K_DIM);
    const int row0 = tid >> 3,         c0 = (tid & 7) ^ (row0 & 7);
    const int row1 = (512 + tid) >> 3, c1 = ((512 + tid) & 7) ^ (row1 & 7);
    unsigned int a00 = (unsigned)(row0 * K_DIM + c0 * 8) * 2u;
    unsigned int a01 = (unsigned)(row1 * K_DIM + c1 * 8) * 2u;
    unsigned int a10 = (unsigned)((128 + row0) * K_DIM + c0 * 8) * 2u;
    unsigned int a11 = (unsigned)((128 + row1) * K_DIM + c1 * 8) * 2u;
    unsigned int b00 = a00, b01 = a01, b10 = a10, b11 = a11;

    #define ST_A0(CURB) do { \
        load16_to_lds(Ab + a00, (char*)&lds[0][0][(CURB)][0] + tid * 16); \
        load16_to_lds(Ab + a01, (char*)&lds[0][0][(CURB)][0] + 8192 + tid * 16); \
        a00 += 128; a01 += 128; } while (0)
    #define ST_A1(CURB) do { \
        load16_to_lds(Ab + a10, (char*)&lds[0][1][(CURB)][0] + tid * 16); \
        load16_to_lds(Ab + a11, (char*)&lds[0][1][(CURB)][0] + 8192 + tid * 16); \
        a10 += 128; a11 += 128; } while (0)
    #define ST_B0(CURB) do { \
        load16_to_lds(Bb + b00, (char*)&lds[1][0][(CURB)][0] + tid * 16); \
        load16_to_lds(Bb + b01, (char*)&lds[1][0][(CURB)][0] + 8192 + tid * 16); \
        b00 += 128; b01 += 128; } while (0)
    #define ST_B1(CURB) do { \
        load16_to_lds(Bb + b10, (char*)&lds[1][1][(CURB)][0] + tid * 16); \
        load16_to_lds(Bb + b11, (char*)&lds[1][1][(CURB)][0] + 8192 + tid * 16); \
        b10 += 128; b11 += 128; } while (0)

    #define MFQUAD(AF, BF, MO, NO) do {                                        \
        _Pragma("unroll")                                                      \
        for (int ks = 0; ks < 2; ++ks)                                         \
            _Pragma("unroll")                                                  \
            for (int mi = 0; mi < 4; ++mi)                                     \
                _Pragma("unroll")                                              \
                for (int nj = 0; nj < 2; ++nj)                                 \
                    acc[(MO) + mi][(NO) + nj] =                                \
                        __builtin_amdgcn_mfma_f32_16x16x32_bf16(               \
                            AF[mi][ks], BF[nj][ks], acc[(MO) + mi][(NO) + nj], \
                            0, 0, 0);                                          \
    } while (0)

    f32x4 acc[8][4];
    #pragma unroll
    for (int i = 0; i < 8; ++i)
        #pragma unroll
        for (int jn = 0; jn < 4; ++jn)
            acc[i][jn] = (f32x4){0.f, 0.f, 0.f, 0.f};

    bf16x8 af[4][2], bf0[2][2], bf1[2][2];

    // prologue: tile0 fully + tile1 {Ah0,Bh0,Bh1}; 14 loads, keep 6 in flight
    ST_A0(0); ST_B0(0); ST_B1(0); ST_A1(0);
    ST_A0(1); ST_B0(1); ST_B1(1);
    VMCNT6();
    BAR();

    auto body = [&](auto curc, int t) {
        constexpr int CUR = decltype(curc)::v;

        // ---- P1: read A-h0(8) + B-h0(4); stage (t+1).Ah1; q00
        #pragma unroll
        for (int mi = 0; mi < 4; ++mi) {
            af[mi][0] = LDA(mi, 0, 0, CUR);
            af[mi][1] = LDA(mi, 1, 0, CUR);
        }
        #pragma unroll
        for (int nj = 0; nj < 2; ++nj) {
            bf0[nj][0] = LDB(nj, 0, 0, CUR);
            bf0[nj][1] = LDB(nj, 1, 0, CUR);
        }
        if (t + 1 < NT) ST_A1(CUR ^ 1);
        BAR();
        __builtin_amdgcn_s_setprio(1);
        MFQUAD(af, bf0, 0, 0);
        __builtin_amdgcn_s_setprio(0);
        BAR();

        // ---- P2: read B-h1(4); stage (t+2).Ah0; q01
        #pragma unroll
        for (int nj = 0; nj < 2; ++nj) {
            bf1[nj][0] = LDB(nj, 0, 1, CUR);
            bf1[nj][1] = LDB(nj, 1, 1, CUR);
        }
        if (t + 2 < NT) ST_A0(CUR);
        BAR();
        __builtin_amdgcn_s_setprio(1);
        MFQUAD(af, bf1, 0, 2);
        __builtin_amdgcn_s_setprio(0);
        BAR();

        // ---- P3' (merged): read A-h1(8); stage (t+2).Bh0+Bh1; vmcnt; q10+q11
        #pragma unroll
        for (int mi = 0; mi < 4; ++mi) {
            af[mi][0] = LDA(mi, 0, 1, CUR);
            af[mi][1] = LDA(mi, 1, 1, CUR);
        }
        if (t + 2 < NT) { ST_B0(CUR); ST_B1(CUR); }
        if (t < NT - 2) { VMCNT6(); } else { VMCNT0(); }
        BAR();
        __builtin_amdgcn_s_setprio(1);
        MFQUAD(af, bf0, 4, 0);
        MFQUAD(af, bf1, 4, 2);
        __builtin_amdgcn_s_setprio(0);
        BAR();
    };

    for (int t = 0; t < NT; t += 2) {
        body(IC<0>{}, t);
        body(IC<1>{}, t + 1);
    }
    #undef LDA
    #undef LDB
    #undef ST_A0
    #undef ST_A1
    #undef ST_B0
    #undef ST_B1
    #undef MFQUAD

    // epilogue: C/D layout col = lane&15 (lr), row = lk*4 + reg; nontemporal
    #pragma unroll
    for (int nj = 0; nj < 4; ++nj) {
        const long col = n0 + (nj >> 1) * 128 + wc * 32 + (nj & 1) * 16 + lr;
        const float bs = bias[col];
        #pragma unroll
        for (int mi = 0; mi < 8; ++mi) {
            const long row = m0 + (mi >> 2) * 128 + wr * 64 + (mi & 3) * 16 + lk * 4;
            #pragma unroll
            for (int r = 0; r < 4; ++r)
                __builtin_nontemporal_store(acc[mi][nj][r] + bs,
                                            &C[(row + r) * (long)N_DIM + col]);
        }
    }
}

// ---- emergency fallback if ws too small: naive fp32 (slow but correct) ----
__global__ void naive_out(const float* __restrict__ x, const float* __restrict__ w,
                          const float* __restrict__ b, float* __restrict__ out) {
    long idx = (long)blockIdx.x * 256 + threadIdx.x;
    if (idx >= (long)M_DIM * N_DIM) return;
    long m = idx / N_DIM;
    int v = (int)(idx - m * N_DIM);
    float s = 0.f;
    for (int h = 0; h < NHEAD; ++h) {
        const float* xr = x + m * K_DIM + h * DMODEL;
        const float* wr = w + ((long)h * DVOCAB + v) * DMODEL;
        float ps = 0.f;
        for (int d = 0; d < DMODEL; ++d) ps += xr[d] * wr[d];
        s += ps + b[h * DVOCAB + v];
    }
    out[idx] = s;
}

extern "C" void kernel_launch(void* const* d_in, const int* in_sizes, int n_in,
                              void* d_out, int out_size, void* d_ws, size_t ws_size,
                              hipStream_t stream) {
    const float* x = (const float*)d_in[0];   // [8,512,8,512]
    const float* w = (const float*)d_in[1];   // [8,32000,512]
    const float* b = (const float*)d_in[2];   // [8,32000]
    float* out = (float*)d_out;               // [8,512,32000]

    const size_t xbf_bytes = (size_t)M_DIM * K_DIM * 2;
    const size_t wbf_bytes = (size_t)N_DIM * K_DIM * 2;
    const size_t bs_bytes  = (size_t)N_DIM * 4;
    const size_t need = xbf_bytes + wbf_bytes + bs_bytes;

    if (ws_size < need) {
        long total = (long)M_DIM * N_DIM;
        int blocks = (int)((total + 255) / 256);
        naive_out<<<blocks, 256, 0, stream>>>(x, w, b, out);
        return;
    }

    unsigned short* xbf = (unsigned short*)d_ws;
    unsigned short* wbf = (unsigned short*)((char*)d_ws + xbf_bytes);
    float* bsum = (float*)((char*)d_ws + xbf_bytes + wbf_bytes);

    prep<<<PREP_W_BLOCKS + PREP_X_BLOCKS + PREP_B_BLOCKS, 256, 0, stream>>>(
        w, x, b, wbf, xbf, bsum);
    gemm256<<<2000, 512, 0, stream>>>(xbf, wbf, bsum, out);  // 16 x 125 tiles
}